// Round 13
// baseline (309.658 us; speedup 1.0000x reference)
//
#include <hip/hip_runtime.h>
#include <math.h>

typedef unsigned short u16;
typedef unsigned int u32;
typedef short bf4 __attribute__((ext_vector_type(4)));
typedef __bf16 bfv8 __attribute__((ext_vector_type(8)));
typedef float f4 __attribute__((ext_vector_type(4)));

#define SEQ 2048
#define HID 2880
#define KPAD 2944
#define QKVN 5120

static __device__ __forceinline__ u16 f2bf(float x) {
  union { float f; u32 u; } v; v.f = x;
  u32 r = v.u + 0x7fffu + ((v.u >> 16) & 1u);
  return (u16)(r >> 16);
}
static __device__ __forceinline__ float bf2f(u16 s) {
  union { u32 u; float f; } v; v.u = ((u32)s) << 16;
  return v.f;
}
static __device__ __forceinline__ void gl_lds16(const void* g, void* l) {
  __builtin_amdgcn_global_load_lds((const __attribute__((address_space(1))) u32*)g,
                                   (__attribute__((address_space(3))) u32*)l, 16, 0, 0);
}
#define MFMA(a, b, c) __builtin_amdgcn_mfma_f32_16x16x16bf16_1k(a, b, c, 0, 0, 0)
#define MFMA32(a, b, c) __builtin_amdgcn_mfma_f32_16x16x32_bf16(a, b, c, 0, 0, 0)
#define BAR __builtin_amdgcn_s_barrier()
#define SCHEDB __builtin_amdgcn_sched_barrier(0)
#define VMCNT0 asm volatile("s_waitcnt vmcnt(0)" ::: "memory")
#define LGKMN(n) asm volatile("s_waitcnt lgkmcnt(" #n ")" ::: "memory")

// ---------------- RMSNorm: x[2048][2880] f32 -> t bf16 [2048][KPAD] ----------------
__global__ __launch_bounds__(256) void k_rmsnorm(const float* __restrict__ x,
                                                 const float* __restrict__ w,
                                                 u16* __restrict__ t) {
  const int row = blockIdx.x;
  const float* xr = x + (size_t)row * HID;
  float ss = 0.f;
  for (int i = threadIdx.x; i < 720; i += 256) {
    float4 v = ((const float4*)xr)[i];
    ss += v.x * v.x + v.y * v.y + v.z * v.z + v.w * v.w;
  }
#pragma unroll
  for (int m = 1; m < 64; m <<= 1) ss += __shfl_xor(ss, m);
  __shared__ float red[4];
  if ((threadIdx.x & 63) == 0) red[threadIdx.x >> 6] = ss;
  __syncthreads();
  float sc = rsqrtf((red[0] + red[1] + red[2] + red[3]) * (1.0f / HID) + 1e-5f);
  u16* tr = t + (size_t)row * KPAD;
  for (int i = threadIdx.x; i < 720; i += 256) {
    float4 v = ((const float4*)xr)[i];
    float4 wv = ((const float4*)w)[i];
    ushort4 o;
    o.x = f2bf(v.x * sc * wv.x);
    o.y = f2bf(v.y * sc * wv.y);
    o.z = f2bf(v.z * sc * wv.z);
    o.w = f2bf(v.w * sc * wv.w);
    ((ushort4*)tr)[i] = o;
  }
  if (threadIdx.x < 16) ((ushort4*)tr)[720 + threadIdx.x] = make_ushort4(0, 0, 0, 0);
}

// ------- transpose+convert: W[K][Nsrc] f32 -> WT[n][Kpad] bf16 (64x64 tiles) -------
__global__ __launch_bounds__(256) void k_convT(const float* __restrict__ W,
                                               u16* __restrict__ WT, int K, int Kpad,
                                               int Nsrc) {
  __shared__ u16 tile[64][65];  // [n_local][k_local]
  const int n0 = blockIdx.x * 64, k0 = blockIdx.y * 64;
  for (int s = threadIdx.x; s < 1024; s += 256) {
    int r = s >> 4, c4 = (s & 15) * 4;
    int kk = k0 + r, nn = n0 + c4;
    float4 v = make_float4(0.f, 0.f, 0.f, 0.f);
    if (kk < K && nn < Nsrc) v = *(const float4*)&W[(size_t)kk * Nsrc + nn];
    tile[c4 + 0][r] = f2bf(v.x);
    tile[c4 + 1][r] = f2bf(v.y);
    tile[c4 + 2][r] = f2bf(v.z);
    tile[c4 + 3][r] = f2bf(v.w);
  }
  __syncthreads();
  for (int s = threadIdx.x; s < 512; s += 256) {
    int r = s >> 3, c8 = (s & 7) * 8;
    u32 p0 = tile[r][c8 + 0] | ((u32)tile[r][c8 + 1] << 16);
    u32 p1 = tile[r][c8 + 2] | ((u32)tile[r][c8 + 3] << 16);
    u32 p2 = tile[r][c8 + 4] | ((u32)tile[r][c8 + 5] << 16);
    u32 p3 = tile[r][c8 + 6] | ((u32)tile[r][c8 + 7] << 16);
    *(uint4*)&WT[(size_t)(n0 + r) * Kpad + k0 + c8] = make_uint4(p0, p1, p2, p3);
  }
}

// -- GEMM 128xBN: A LDS-staged (gl_lds, XOR swizzle), B DIRECT global->register
// -- (zero intra-block B reuse -> skip LDS; L2-resident via XCD-grouped grid).
// -- 4 waves (2Mx2N), 2 blocks/CU, 1 barrier/tile, aged vmcnt, mf-major lgkm ladder.
// C[M][N] = A[M][K] * BT[N][K]^T.  Grid 512 = 8 XCD x (4 n-panels x 16 m).
template <int MODE, int BN>  // MODE 0: bf16 ; 1: f32 + residual, guard col<Nout
__global__ __launch_bounds__(256, 2) void k_gemm10(const u16* __restrict__ A,
                                                   const u16* __restrict__ BT,
                                                   void* __restrict__ Cv,
                                                   const float* __restrict__ resid,
                                                   int N, int Nout, int K) {
  constexpr int WN = BN / 2;       // wave n-extent (80 or 48)
  constexpr int NF = WN / 16;      // B frags per wave (5 or 3)
  constexpr int ATILE = 16384;     // A K-tile bytes (128 rows x 64 k x 2B)
  __shared__ __align__(16) char lds[2 * ATILE];
  const int bid = blockIdx.x;
  const int xcd = bid & 7, idx = bid >> 3;
  const int n0 = (xcd * 4 + (idx >> 4)) * BN;  // 4 n-panels per XCD -> B L2-resident
  const int m0 = (idx & 15) * 128;
  const int tid = threadIdx.x;     // 0..255, 4 waves
  const int l = tid & 63, w = tid >> 6;
  const int wm = w >> 1, wn = w & 1;  // 2M x 2N waves
  const int g = l >> 4, q = l & 15;
  const int NT = K >> 6;
  const u16* bBase = BT + (size_t)(n0 + wn * WN + q) * K + g * 8;

#define STAGE_A(bo_, kt) { _Pragma("unroll") for (int p = 0; p < 4; ++p) { \
    const int slot = p * 256 + tid; \
    const int row = slot >> 3, c = slot & 7; \
    gl_lds16(A + (size_t)(m0 + row) * K + (kt)*64 + ((c ^ (row & 7)) * 8), \
             lds + (bo_) + slot * 16); } }
#define BLOAD(DST, kt) { _Pragma("unroll") for (int nf = 0; nf < NF; ++nf) { \
    const u16* p_ = bBase + (size_t)(nf * 16) * K + (kt)*64; \
    DST[nf][0] = *(const bfv8*)(p_); \
    DST[nf][1] = *(const bfv8*)(p_ + 32); } }
#define LDA2(mf_, bo_) { const int r_ = wm * 64 + (mf_)*16 + q; \
    af[mf_][0] = *(const bfv8*)(lds + (bo_) + r_ * 128 + (((g) ^ (r_ & 7)) << 4)); \
    af[mf_][1] = *(const bfv8*)(lds + (bo_) + r_ * 128 + (((4 + g) ^ (r_ & 7)) << 4)); }
#define MMROW(mf_, BC) { _Pragma("unroll") for (int nf = 0; nf < NF; ++nf) { \
    acc[mf_][nf] = MFMA32(af[mf_][0], BC[nf][0], acc[mf_][nf]); \
    acc[mf_][nf] = MFMA32(af[mf_][1], BC[nf][1], acc[mf_][nf]); } }

// one K-tile: issue next-tile A stages + B reg-loads; A-frag lgkm ladder; drain; bar
#define TB(t_, BC, BNX) { \
    const int t__ = (t_); const bool pf__ = (t__ + 1 < NT); \
    const int bo = (t__ & 1) * ATILE, so = bo ^ ATILE; \
    if (pf__) { STAGE_A(so, t__ + 1); BLOAD(BNX, t__ + 1); } \
    SCHEDB; \
    LDA2(0, bo); SCHEDB; LDA2(1, bo); SCHEDB; \
    LDA2(2, bo); SCHEDB; LDA2(3, bo); SCHEDB; \
    __builtin_amdgcn_s_setprio(1); \
    LGKMN(6); SCHEDB; MMROW(0, BC); \
    LGKMN(4); SCHEDB; MMROW(1, BC); \
    LGKMN(2); SCHEDB; MMROW(2, BC); \
    LGKMN(0); SCHEDB; MMROW(3, BC); \
    __builtin_amdgcn_s_setprio(0); \
    VMCNT0;  /* t+1 stages + B loads: issued at tile start, aged ~full tile */ \
    SCHEDB; BAR; \
  }

  f4 acc[4][NF] = {};
  bfv8 af[4][2], bcP[NF][2], bcQ[NF][2];

  // prologue: stage A tile 0, load B tile 0 to regs, drain, barrier
  STAGE_A(0, 0);
  BLOAD(bcP, 0);
  VMCNT0; SCHEDB; BAR;

  for (int t = 0; t < NT; t += 2) {  // NT even (46 / 64)
    TB(t, bcP, bcQ);
    TB(t + 1, bcQ, bcP);
  }
  // epilogue
#pragma unroll
  for (int mf = 0; mf < 4; ++mf)
#pragma unroll
    for (int nf = 0; nf < NF; ++nf)
#pragma unroll
      for (int r = 0; r < 4; ++r) {
        int row = m0 + wm * 64 + mf * 16 + g * 4 + r;
        int col = n0 + wn * WN + nf * 16 + q;
        if constexpr (MODE == 0) {
          ((u16*)Cv)[(size_t)row * N + col] = f2bf(acc[mf][nf][r]);
        } else {
          if (col < Nout)
            ((float*)Cv)[(size_t)row * Nout + col] =
                acc[mf][nf][r] + resid[(size_t)row * Nout + col];
        }
      }
#undef STAGE_A
#undef BLOAD
#undef LDA2
#undef MMROW
#undef TB
}

// ------- RoPE (YaRN/NTK), IN-PLACE on qkv; 1 block/token, LDS cos/sin table -------
__global__ __launch_bounds__(256) void k_rope(u16* __restrict__ qkv) {
  __shared__ float lcs[64];  // [0:32) cos, [32:64) sin
  const int t = blockIdx.x;
  if (threadIdx.x < 32) {
    const int d = threadIdx.x;
    const float low = 8.0927791f, high = 17.3980236f, conc = 1.3465735903f;
    float freq = powf(150000.0f, (float)d * (1.0f / 32.0f));
    float r01 = fminf(fmaxf(((float)d - low) / (high - low), 0.f), 1.f);
    float invf = (1.0f / (32.0f * freq)) * r01 + (1.0f / freq) * (1.f - r01);
    float ang = (float)t * invf;
    lcs[d] = cosf(ang) * conc;
    lcs[d + 32] = sinf(ang) * conc;
  }
  __syncthreads();
  for (int i = threadIdx.x; i < 2304; i += 256) {  // 72 heads * 32 pairs
    const int d = i & 31, hd = i >> 5;
    u16* base = qkv + (size_t)t * QKVN + (hd < 64 ? hd * 64 : 4096 + (hd - 64) * 64);
    float cc = lcs[d], ss = lcs[d + 32];
    float x1 = bf2f(base[d]), x2 = bf2f(base[d + 32]);
    base[d] = f2bf(x1 * cc - x2 * ss);
    base[d + 32] = f2bf(x2 * cc + x1 * ss);
  }
}

// ---------------- V transpose: qkv v-cols -> vt[8][64][2048] bf16 ----------------
__global__ __launch_bounds__(256) void k_vtrans(const u16* __restrict__ qkv,
                                                u16* __restrict__ vt) {
  __shared__ u16 tile[64][72];  // [t_local][d]
  const int t0 = blockIdx.x * 64, h = blockIdx.y;
  for (int s = threadIdx.x; s < 512; s += 256) {
    int r = s >> 3, c8 = (s & 7) * 8;
    uint4 v = *(const uint4*)&qkv[(size_t)(t0 + r) * QKVN + 4608 + h * 64 + c8];
    *(uint4*)&tile[r][c8] = v;
  }
  __syncthreads();
  for (int s = threadIdx.x; s < 512; s += 256) {
    int d = s >> 3, c8 = (s & 7) * 8;
    u32 p0 = tile[c8 + 0][d] | ((u32)tile[c8 + 1][d] << 16);
    u32 p1 = tile[c8 + 2][d] | ((u32)tile[c8 + 3][d] << 16);
    u32 p2 = tile[c8 + 4][d] | ((u32)tile[c8 + 5][d] << 16);
    u32 p3 = tile[c8 + 6][d] | ((u32)tile[c8 + 7][d] << 16);
    *(uint4*)&vt[((size_t)h * 64 + d) * SEQ + t0 + c8] = make_uint4(p0, p1, p2, p3);
  }
}

// ---------------- Attention: sliding window 128 + sink, GQA 8x8 ----------------
__global__ __launch_bounds__(512) void k_attn(const u16* __restrict__ qkv,
                                              const u16* __restrict__ vt,
                                              const float* __restrict__ sinks,
                                              u16* __restrict__ attn) {
  __shared__ u16 lK[144 * 72];       // [key][dim], stride 72
  __shared__ u16 lV[64 * 152];       // [dim][key], stride 152
  __shared__ u16 lP[8 * 16 * 148];   // per-wave [q][key], stride 148
  const int t0 = blockIdx.x * 16;
  const int h = blockIdx.y;
  const int j0 = t0 - 128;
  const int tid = threadIdx.x;
  for (int s = tid; s < 1152; s += 512) {
    int row = s >> 3, c = s & 7;
    int j = j0 + row;
    uint4 v = make_uint4(0, 0, 0, 0);
    if (j >= 0) v = *(const uint4*)&qkv[(size_t)j * QKVN + 4096 + h * 64 + c * 8];
    *(uint4*)&lK[row * 72 + c * 8] = v;
  }
  for (int s = tid; s < 1152; s += 512) {
    int d = s / 18, c = s - d * 18;
    int jb = j0 + c * 8;
    uint4 v = make_uint4(0, 0, 0, 0);
    if (jb >= 0) v = *(const uint4*)&vt[((size_t)h * 64 + d) * SEQ + jb];
    *(uint4*)&lV[d * 152 + c * 8] = v;
  }
  __syncthreads();
  const int w = tid >> 6, l = tid & 63;
  const int g = l >> 4, q = l & 15;
  const int hq = h * 8 + w;
  const float sink = sinks[hq];
  bf4 qf[4];
  const u16* qrow = qkv + (size_t)(t0 + q) * QKVN + hq * 64;
#pragma unroll
  for (int ks = 0; ks < 4; ++ks) qf[ks] = *(const bf4*)&qrow[ks * 16 + g * 4];
  f4 sacc[9];
#pragma unroll
  for (int nt = 0; nt < 9; ++nt) {
    f4 z = {0.f, 0.f, 0.f, 0.f};
    sacc[nt] = z;
#pragma unroll
    for (int ks = 0; ks < 4; ++ks) {
      bf4 kf = *(const bf4*)&lK[(nt * 16 + q) * 72 + ks * 16 + g * 4];
      sacc[nt] = MFMA(qf[ks], kf, sacc[nt]);
    }
  }
  const float NEG = -__builtin_inff();
  float rmax[4] = {NEG, NEG, NEG, NEG};
#pragma unroll
  for (int nt = 0; nt < 9; ++nt)
#pragma unroll
    for (int r = 0; r < 4; ++r) {
      float sv = sacc[nt][r] * 0.125f;
      int it = t0 + g * 4 + r;
      int j = j0 + nt * 16 + q;
      bool ban = (j > it) || (it - j >= 128) || (j < 0);
      sv = ban ? NEG : sv;
      sacc[nt][r] = sv;
      rmax[r] = fmaxf(rmax[r], sv);
    }
#pragma unroll
  for (int r = 0; r < 4; ++r)
#pragma unroll
    for (int m = 1; m < 16; m <<= 1) rmax[r] = fmaxf(rmax[r], __shfl_xor(rmax[r], m));
  float ssum[4];
  u16* pbase = lP + w * (16 * 148);
#pragma unroll
  for (int r = 0; r < 4; ++r) {
    float mf = fmaxf(rmax[r], sink);
    float ps = 0.f;
#pragma unroll
    for (int nt = 0; nt < 9; ++nt) {
      float p = __expf(sacc[nt][r] - mf);
      pbase[(g * 4 + r) * 148 + nt * 16 + q] = f2bf(p);
      ps += p;
    }
#pragma unroll
    for (int m = 1; m < 16; m <<= 1) ps += __shfl_xor(ps, m);
    ssum[r] = ps + __expf(sink - mf);
  }
  f4 oacc[4] = {};
#pragma unroll
  for (int kt = 0; kt < 9; ++kt) {
    bf4 pa = *(const bf4*)&pbase[q * 148 + kt * 16 + g * 4];
#pragma unroll
    for (int nt = 0; nt < 4; ++nt) {
      bf4 vf = *(const bf4*)&lV[(nt * 16 + q) * 152 + kt * 16 + g * 4];
      oacc[nt] = MFMA(pa, vf, oacc[nt]);
    }
  }
#pragma unroll
  for (int nt = 0; nt < 4; ++nt)
#pragma unroll
    for (int r = 0; r < 4; ++r) {
      int row = t0 + g * 4 + r;
      attn[(size_t)row * 4096 + hq * 64 + nt * 16 + q] = f2bf(oacc[nt][r] / ssum[r]);
    }
}

extern "C" void kernel_launch(void* const* d_in, const int* in_sizes, int n_in,
                              void* d_out, int out_size, void* d_ws, size_t ws_size,
                              hipStream_t stream) {
  const float* x = (const float*)d_in[0];
  const float* norm_w = (const float*)d_in[1];
  const float* qkv_w = (const float*)d_in[2];
  const float* out_w = (const float*)d_in[3];
  const float* sinks = (const float*)d_in[4];
  float* out = (float*)d_out;
  char* ws = (char*)d_ws;
  // ws layout (bytes), total 90,439,680:
  u16* t     = (u16*)(ws);               // [2048][2944] = 12,058,624
  u16* wqkvT = (u16*)(ws + 12058624);    // [5120][2944] = 30,146,560 -> 42,205,184
  u16* qkv   = (u16*)(ws + 42205184);    // [2048][5120] = 20,971,520 -> 63,176,704
  u16* vt    = (u16*)(ws + 63176704);    // [8][64][2048] = 2,097,152 -> 65,273,856
  u16* woutT = (u16*)(ws + 65273856);    // [3072][4096] = 25,165,824 -> 90,439,680
  u16* attnO = (u16*)(ws);               // alias t+wqkvT head (dead after QKV GEMM), 16.8 MB

  k_rmsnorm<<<dim3(2048), dim3(256), 0, stream>>>(x, norm_w, t);
  k_convT<<<dim3(80, 46), dim3(256), 0, stream>>>(qkv_w, wqkvT, 2880, KPAD, 5120);
  k_convT<<<dim3(48, 64), dim3(256), 0, stream>>>(out_w, woutT, 4096, 4096, 2880);
  // QKV: C[2048][5120], tile 128x160, 512 blocks (XCD-grouped), NT=46 even
  k_gemm10<0, 160><<<dim3(512), dim3(256), 0, stream>>>(t, wqkvT, (void*)qkv,
                                                        nullptr, 5120, 5120, KPAD);
  k_rope<<<dim3(2048), dim3(256), 0, stream>>>(qkv);
  k_vtrans<<<dim3(32, 8), dim3(256), 0, stream>>>(qkv, vt);
  k_attn<<<dim3(128, 8), dim3(512), 0, stream>>>(qkv, vt, sinks, attnO);
  // out-proj: C[2048][2880] (N padded 3072), tile 128x96, 512 blocks, NT=64 even
  k_gemm10<1, 96><<<dim3(512), dim3(256), 0, stream>>>(attnO, woutT, (void*)out,
                                                       x, 3072, 2880, 4096);
}

// Round 14
// 176.977 us; speedup vs baseline: 1.7497x; 1.7497x over previous
//
#include <hip/hip_runtime.h>
#include <math.h>

typedef unsigned short u16;
typedef unsigned int u32;
typedef short bf4 __attribute__((ext_vector_type(4)));
typedef __bf16 bfv8 __attribute__((ext_vector_type(8)));
typedef float f4 __attribute__((ext_vector_type(4)));

#define SEQ 2048
#define HID 2880
#define KPAD 2944
#define QKVN 5120

static __device__ __forceinline__ u16 f2bf(float x) {
  union { float f; u32 u; } v; v.f = x;
  u32 r = v.u + 0x7fffu + ((v.u >> 16) & 1u);
  return (u16)(r >> 16);
}
static __device__ __forceinline__ float bf2f(u16 s) {
  union { u32 u; float f; } v; v.u = ((u32)s) << 16;
  return v.f;
}
static __device__ __forceinline__ void gl_lds16(const void* g, void* l) {
  __builtin_amdgcn_global_load_lds((const __attribute__((address_space(1))) u32*)g,
                                   (__attribute__((address_space(3))) u32*)l, 16, 0, 0);
}
#define MFMA(a, b, c) __builtin_amdgcn_mfma_f32_16x16x16bf16_1k(a, b, c, 0, 0, 0)
#define MFMA32(a, b, c) __builtin_amdgcn_mfma_f32_16x16x32_bf16(a, b, c, 0, 0, 0)
#define BAR __builtin_amdgcn_s_barrier()
#define SCHEDB __builtin_amdgcn_sched_barrier(0)
#define VMCNT0 asm volatile("s_waitcnt vmcnt(0)" ::: "memory")
#define LGKM0 asm volatile("s_waitcnt lgkmcnt(0)" ::: "memory")
#define LGKM2 asm volatile("s_waitcnt lgkmcnt(2)" ::: "memory")

// -------- RMSNorm: x[2048][2880] f32 -> t bf16 [2048][KPAD]; also writes rope table
__global__ __launch_bounds__(256) void k_rmsnorm(const float* __restrict__ x,
                                                 const float* __restrict__ w,
                                                 u16* __restrict__ t,
                                                 float* __restrict__ tab) {
  const int row = blockIdx.x;
  // rope cos/sin table for token `row` (YaRN/NTK), hidden under memory latency
  if (threadIdx.x < 32) {
    const int d = threadIdx.x;
    const float low = 8.0927791f, high = 17.3980236f, conc = 1.3465735903f;
    float freq = powf(150000.0f, (float)d * (1.0f / 32.0f));
    float r01 = fminf(fmaxf(((float)d - low) / (high - low), 0.f), 1.f);
    float invf = (1.0f / (32.0f * freq)) * r01 + (1.0f / freq) * (1.f - r01);
    float ang = (float)row * invf;
    tab[(size_t)row * 64 + d] = cosf(ang) * conc;
    tab[(size_t)row * 64 + 32 + d] = sinf(ang) * conc;
  }
  const float* xr = x + (size_t)row * HID;
  float ss = 0.f;
  for (int i = threadIdx.x; i < 720; i += 256) {
    float4 v = ((const float4*)xr)[i];
    ss += v.x * v.x + v.y * v.y + v.z * v.z + v.w * v.w;
  }
#pragma unroll
  for (int m = 1; m < 64; m <<= 1) ss += __shfl_xor(ss, m);
  __shared__ float red[4];
  if ((threadIdx.x & 63) == 0) red[threadIdx.x >> 6] = ss;
  __syncthreads();
  float sc = rsqrtf((red[0] + red[1] + red[2] + red[3]) * (1.0f / HID) + 1e-5f);
  u16* tr = t + (size_t)row * KPAD;
  for (int i = threadIdx.x; i < 720; i += 256) {
    float4 v = ((const float4*)xr)[i];
    float4 wv = ((const float4*)w)[i];
    ushort4 o;
    o.x = f2bf(v.x * sc * wv.x);
    o.y = f2bf(v.y * sc * wv.y);
    o.z = f2bf(v.z * sc * wv.z);
    o.w = f2bf(v.w * sc * wv.w);
    ((ushort4*)tr)[i] = o;
  }
  if (threadIdx.x < 16) ((ushort4*)tr)[720 + threadIdx.x] = make_ushort4(0, 0, 0, 0);
}

// ------- transpose+convert: W[K][Nsrc] f32 -> WT[n][Kpad] bf16 (64x64 tiles) -------
__global__ __launch_bounds__(256) void k_convT(const float* __restrict__ W,
                                               u16* __restrict__ WT, int K, int Kpad,
                                               int Nsrc) {
  __shared__ u16 tile[64][65];  // [n_local][k_local]
  const int n0 = blockIdx.x * 64, k0 = blockIdx.y * 64;
  for (int s = threadIdx.x; s < 1024; s += 256) {
    int r = s >> 4, c4 = (s & 15) * 4;
    int kk = k0 + r, nn = n0 + c4;
    float4 v = make_float4(0.f, 0.f, 0.f, 0.f);
    if (kk < K && nn < Nsrc) v = *(const float4*)&W[(size_t)kk * Nsrc + nn];
    tile[c4 + 0][r] = f2bf(v.x);
    tile[c4 + 1][r] = f2bf(v.y);
    tile[c4 + 2][r] = f2bf(v.z);
    tile[c4 + 3][r] = f2bf(v.w);
  }
  __syncthreads();
  for (int s = threadIdx.x; s < 512; s += 256) {
    int r = s >> 3, c8 = (s & 7) * 8;
    u32 p0 = tile[r][c8 + 0] | ((u32)tile[r][c8 + 1] << 16);
    u32 p1 = tile[r][c8 + 2] | ((u32)tile[r][c8 + 3] << 16);
    u32 p2 = tile[r][c8 + 4] | ((u32)tile[r][c8 + 5] << 16);
    u32 p3 = tile[r][c8 + 6] | ((u32)tile[r][c8 + 7] << 16);
    *(uint4*)&WT[(size_t)(n0 + r) * Kpad + k0 + c8] = make_uint4(p0, p1, p2, p3);
  }
}

// -- GEMM 128xBN, BK=64, 4 waves (2Mx2N), 2 blocks/CU, 1-barrier counted-lgkm loop --
// (R9 best-measured structure, verbatim.)  C[M][N] = A[M][K] * BT[N][K]^T.
template <int MODE, int BN>  // MODE 0: bf16 ; 1: f32 + residual, guard col<Nout
__global__ __launch_bounds__(256, 2) void k_gemm6(const u16* __restrict__ A,
                                                  const u16* __restrict__ BT,
                                                  void* __restrict__ Cv,
                                                  const float* __restrict__ resid,
                                                  int N, int Nout, int K) {
  constexpr int WN = BN / 2;      // wave n-extent (80 or 48)
  constexpr int NF = WN / 16;     // B chunks per wave (5 or 3)
  constexpr int ABY = 128 * 128;  // A K-tile bytes (16 KB)
  constexpr int BBY = BN * 128;   // B K-tile bytes (20 / 12 KB)
  constexpr int TILE = ABY + BBY;
  constexpr int NBC = BBY / 4096; // B stage calls (256 thr x 16B)
  __shared__ __align__(16) char lds[2 * TILE];
  const int n0 = blockIdx.x * BN, m0 = blockIdx.y * 128;
  const int tid = threadIdx.x;    // 0..255, 4 waves
  const int l = tid & 63, w = tid >> 6;
  const int wm = w >> 1, wn = w & 1;  // 2M x 2N waves
  const int g = l >> 4, q = l & 15;
  const int NT = K >> 6;

#define STAGE_A(bo_, kt, p) { const int slot = (p)*256 + tid; \
    const int row = slot >> 3, c = slot & 7; \
    gl_lds16(A + (size_t)(m0 + row) * K + (kt)*64 + ((c ^ (row & 7)) * 8), \
             lds + (bo_) + slot * 16); }
#define STAGE_B(bo_, kt, p) { const int slot = (p)*256 + tid; \
    const int row = slot >> 3, c = slot & 7; \
    gl_lds16(BT + (size_t)(n0 + row) * K + (kt)*64 + ((c ^ (row & 7)) * 8), \
             lds + (bo_) + ABY + slot * 16); }
#define LDB2(DST, nf_) { const int r_ = wn * WN + (nf_)*16 + q; \
    DST[0] = *(const bfv8*)(lds + bo + ABY + r_ * 128 + (((g) ^ (r_ & 7)) << 4)); \
    DST[1] = *(const bfv8*)(lds + bo + ABY + r_ * 128 + (((4 + g) ^ (r_ & 7)) << 4)); }

  f4 acc[4][NF] = {};
  // prologue: stage tile 0, drain, barrier
#pragma unroll
  for (int p = 0; p < 4; ++p) STAGE_A(0, 0, p);
#pragma unroll
  for (int p = 0; p < NBC; ++p) STAGE_B(0, 0, p);
  VMCNT0; SCHEDB; BAR;

  for (int t = 0; t < NT; ++t) {
    const int bo = (t & 1) * TILE;  // current buffer
    const int so = bo ^ TILE;       // stage buffer (next tile)
    // issue next-tile stages first (latency covered by this tile's compute)
    if (t + 1 < NT) {
#pragma unroll
      for (int p = 0; p < 4; ++p) STAGE_A(so, t + 1, p);
#pragma unroll
      for (int p = 0; p < NBC; ++p) STAGE_B(so, t + 1, p);
    }
    SCHEDB;
    bfv8 af[4][2], bb[2][2];
    // entry: A frags (8 reads) + B chunk 0 (2 reads) | B chunk 1 (2 reads)
#pragma unroll
    for (int mf = 0; mf < 4; ++mf) {
      const int r = wm * 64 + mf * 16 + q;
      af[mf][0] = *(const bfv8*)(lds + bo + r * 128 + (((g) ^ (r & 7)) << 4));
      af[mf][1] = *(const bfv8*)(lds + bo + r * 128 + (((4 + g) ^ (r & 7)) << 4));
    }
    LDB2(bb[0], 0);
    SCHEDB;                 // pin boundary: [A,b0] | b1
    LDB2(bb[1], 1);
    __builtin_amdgcn_s_setprio(1);
#pragma unroll
    for (int nf = 0; nf < NF; ++nf) {
      if (nf == NF - 1) { LGKM0; } else { LGKM2; }  // chunk nf landed; nf+1 in flight
      SCHEDB;
#pragma unroll
      for (int mf = 0; mf < 4; ++mf) {
        acc[mf][nf] = MFMA32(af[mf][0], bb[nf & 1][0], acc[mf][nf]);
        acc[mf][nf] = MFMA32(af[mf][1], bb[nf & 1][1], acc[mf][nf]);
      }
      if (nf + 2 < NF) LDB2(bb[nf & 1], nf + 2);  // refill freed slot
    }
    __builtin_amdgcn_s_setprio(0);
    VMCNT0;  // next-tile stages issued at tile start: aged ~1 full tile -> near-free
    SCHEDB; BAR;
  }
  // epilogue
#pragma unroll
  for (int mf = 0; mf < 4; ++mf)
#pragma unroll
    for (int nf = 0; nf < NF; ++nf)
#pragma unroll
      for (int r = 0; r < 4; ++r) {
        int row = m0 + wm * 64 + mf * 16 + g * 4 + r;
        int col = n0 + wn * WN + nf * 16 + q;
        if constexpr (MODE == 0) {
          ((u16*)Cv)[(size_t)row * N + col] = f2bf(acc[mf][nf][r]);
        } else {
          if (col < Nout)
            ((float*)Cv)[(size_t)row * Nout + col] =
                acc[mf][nf][r] + resid[(size_t)row * Nout + col];
        }
      }
#undef STAGE_A
#undef STAGE_B
#undef LDB2
}

// ---------------- V transpose: qkv v-cols -> vt[8][64][2048] bf16 ----------------
__global__ __launch_bounds__(256) void k_vtrans(const u16* __restrict__ qkv,
                                                u16* __restrict__ vt) {
  __shared__ u16 tile[64][72];  // [t_local][d]
  const int t0 = blockIdx.x * 64, h = blockIdx.y;
  for (int s = threadIdx.x; s < 512; s += 256) {
    int r = s >> 3, c8 = (s & 7) * 8;
    uint4 v = *(const uint4*)&qkv[(size_t)(t0 + r) * QKVN + 4608 + h * 64 + c8];
    *(uint4*)&tile[r][c8] = v;
  }
  __syncthreads();
  for (int s = threadIdx.x; s < 512; s += 256) {
    int d = s >> 3, c8 = (s & 7) * 8;
    u32 p0 = tile[c8 + 0][d] | ((u32)tile[c8 + 1][d] << 16);
    u32 p1 = tile[c8 + 2][d] | ((u32)tile[c8 + 3][d] << 16);
    u32 p2 = tile[c8 + 4][d] | ((u32)tile[c8 + 5][d] << 16);
    u32 p3 = tile[c8 + 6][d] | ((u32)tile[c8 + 7][d] << 16);
    *(uint4*)&vt[((size_t)h * 64 + d) * SEQ + t0 + c8] = make_uint4(p0, p1, p2, p3);
  }
}

// ------- Attention: sliding window 128 + sink, GQA 8x8, RoPE fused (table) -------
__global__ __launch_bounds__(512) void k_attn(const u16* __restrict__ qkv,
                                              const u16* __restrict__ vt,
                                              const float* __restrict__ sinks,
                                              const float* __restrict__ tab,
                                              u16* __restrict__ attn) {
  __shared__ u16 lK[144 * 72];       // [key][dim], stride 72
  __shared__ u16 lV[64 * 152];       // [dim][key], stride 152
  __shared__ u16 lP[8 * 16 * 148];   // per-wave [q][key], stride 148
  const int t0 = blockIdx.x * 16;
  const int h = blockIdx.y;
  const int j0 = t0 - 128;
  const int tid = threadIdx.x;
  // stage RAW K rows (zero for j<0)
  for (int s = tid; s < 1152; s += 512) {
    int row = s >> 3, c = s & 7;
    int j = j0 + row;
    uint4 v = make_uint4(0, 0, 0, 0);
    if (j >= 0) v = *(const uint4*)&qkv[(size_t)j * QKVN + 4096 + h * 64 + c * 8];
    *(uint4*)&lK[row * 72 + c * 8] = v;
  }
  for (int s = tid; s < 1152; s += 512) {
    int d = s / 18, c = s - d * 18;
    int jb = j0 + c * 8;
    uint4 v = make_uint4(0, 0, 0, 0);
    if (jb >= 0) v = *(const uint4*)&vt[((size_t)h * 64 + d) * SEQ + jb];
    *(uint4*)&lV[d * 152 + c * 8] = v;
  }
  __syncthreads();
  // fused RoPE on K rows in LDS: 144 rows x 32 pairs
  for (int p = tid; p < 4608; p += 512) {
    int row = p >> 5, d = p & 31;
    int j = j0 + row;
    if (j >= 0) {
      float c = tab[(size_t)j * 64 + d];
      float s = tab[(size_t)j * 64 + 32 + d];
      int base = row * 72;
      float x1 = bf2f(lK[base + d]), x2 = bf2f(lK[base + 32 + d]);
      lK[base + d] = f2bf(x1 * c - x2 * s);
      lK[base + 32 + d] = f2bf(x2 * c + x1 * s);
    }
  }
  __syncthreads();
  const int w = tid >> 6, l = tid & 63;
  const int g = l >> 4, q = l & 15;
  const int hq = h * 8 + w;
  const float sink = sinks[hq];
  // load RAW Q fragments, apply RoPE in registers (pairs: ks0<->ks2, ks1<->ks3)
  bf4 qf[4];
  const u16* qrow = qkv + (size_t)(t0 + q) * QKVN + hq * 64;
#pragma unroll
  for (int ks = 0; ks < 4; ++ks) qf[ks] = *(const bf4*)&qrow[ks * 16 + g * 4];
  {
    const float* tb = tab + (size_t)(t0 + q) * 64;
    float c0[4], s0[4], c1[4], s1[4];
    *(float4*)c0 = *(const float4*)&tb[g * 4];
    *(float4*)s0 = *(const float4*)&tb[32 + g * 4];
    *(float4*)c1 = *(const float4*)&tb[16 + g * 4];
    *(float4*)s1 = *(const float4*)&tb[48 + g * 4];
#pragma unroll
    for (int i = 0; i < 4; ++i) {
      float x0 = bf2f((u16)qf[0][i]), x2 = bf2f((u16)qf[2][i]);
      qf[0][i] = (short)f2bf(x0 * c0[i] - x2 * s0[i]);
      qf[2][i] = (short)f2bf(x2 * c0[i] + x0 * s0[i]);
      float x1 = bf2f((u16)qf[1][i]), x3 = bf2f((u16)qf[3][i]);
      qf[1][i] = (short)f2bf(x1 * c1[i] - x3 * s1[i]);
      qf[3][i] = (short)f2bf(x3 * c1[i] + x1 * s1[i]);
    }
  }
  f4 sacc[9];
#pragma unroll
  for (int nt = 0; nt < 9; ++nt) {
    f4 z = {0.f, 0.f, 0.f, 0.f};
    sacc[nt] = z;
#pragma unroll
    for (int ks = 0; ks < 4; ++ks) {
      bf4 kf = *(const bf4*)&lK[(nt * 16 + q) * 72 + ks * 16 + g * 4];
      sacc[nt] = MFMA(qf[ks], kf, sacc[nt]);
    }
  }
  const float NEG = -__builtin_inff();
  float rmax[4] = {NEG, NEG, NEG, NEG};
#pragma unroll
  for (int nt = 0; nt < 9; ++nt)
#pragma unroll
    for (int r = 0; r < 4; ++r) {
      float sv = sacc[nt][r] * 0.125f;
      int it = t0 + g * 4 + r;
      int j = j0 + nt * 16 + q;
      bool ban = (j > it) || (it - j >= 128) || (j < 0);
      sv = ban ? NEG : sv;
      sacc[nt][r] = sv;
      rmax[r] = fmaxf(rmax[r], sv);
    }
#pragma unroll
  for (int r = 0; r < 4; ++r)
#pragma unroll
    for (int m = 1; m < 16; m <<= 1) rmax[r] = fmaxf(rmax[r], __shfl_xor(rmax[r], m));
  float ssum[4];
  u16* pbase = lP + w * (16 * 148);
#pragma unroll
  for (int r = 0; r < 4; ++r) {
    float mf = fmaxf(rmax[r], sink);
    float ps = 0.f;
#pragma unroll
    for (int nt = 0; nt < 9; ++nt) {
      float p = __expf(sacc[nt][r] - mf);
      pbase[(g * 4 + r) * 148 + nt * 16 + q] = f2bf(p);
      ps += p;
    }
#pragma unroll
    for (int m = 1; m < 16; m <<= 1) ps += __shfl_xor(ps, m);
    ssum[r] = ps + __expf(sink - mf);
  }
  f4 oacc[4] = {};
#pragma unroll
  for (int kt = 0; kt < 9; ++kt) {
    bf4 pa = *(const bf4*)&pbase[q * 148 + kt * 16 + g * 4];
#pragma unroll
    for (int nt = 0; nt < 4; ++nt) {
      bf4 vf = *(const bf4*)&lV[(nt * 16 + q) * 152 + kt * 16 + g * 4];
      oacc[nt] = MFMA(pa, vf, oacc[nt]);
    }
  }
#pragma unroll
  for (int nt = 0; nt < 4; ++nt)
#pragma unroll
    for (int r = 0; r < 4; ++r) {
      int row = t0 + g * 4 + r;
      attn[(size_t)row * 4096 + hq * 64 + nt * 16 + q] = f2bf(oacc[nt][r] / ssum[r]);
    }
}

extern "C" void kernel_launch(void* const* d_in, const int* in_sizes, int n_in,
                              void* d_out, int out_size, void* d_ws, size_t ws_size,
                              hipStream_t stream) {
  const float* x = (const float*)d_in[0];
  const float* norm_w = (const float*)d_in[1];
  const float* qkv_w = (const float*)d_in[2];
  const float* out_w = (const float*)d_in[3];
  const float* sinks = (const float*)d_in[4];
  float* out = (float*)d_out;
  char* ws = (char*)d_ws;
  // ws layout (bytes), total 90,963,968:
  u16* t     = (u16*)(ws);               // [2048][2944] = 12,058,624
  u16* wqkvT = (u16*)(ws + 12058624);    // [5120][2944] = 30,146,560 -> 42,205,184
  u16* qkv   = (u16*)(ws + 42205184);    // [2048][5120] = 20,971,520 -> 63,176,704
  u16* vt    = (u16*)(ws + 63176704);    // [8][64][2048] = 2,097,152 -> 65,273,856
  u16* woutT = (u16*)(ws + 65273856);    // [3072][4096] = 25,165,824 -> 90,439,680
  float* tab = (float*)(ws + 90439680);  // [2048][64] f32 = 524,288 -> 90,963,968
  u16* attnO = (u16*)(ws);               // alias t+wqkvT head (dead after QKV GEMM)

  k_rmsnorm<<<dim3(2048), dim3(256), 0, stream>>>(x, norm_w, t, tab);
  k_convT<<<dim3(80, 46), dim3(256), 0, stream>>>(qkv_w, wqkvT, 2880, KPAD, 5120);
  k_convT<<<dim3(48, 64), dim3(256), 0, stream>>>(out_w, woutT, 4096, 4096, 2880);
  // QKV: C[2048][5120], tile 128x160, grid (32,16) = 512 blocks (2/CU, 4 waves each)
  k_gemm6<0, 160><<<dim3(32, 16), dim3(256), 0, stream>>>(t, wqkvT, (void*)qkv,
                                                          nullptr, 5120, 5120, KPAD);
  k_vtrans<<<dim3(32, 8), dim3(256), 0, stream>>>(qkv, vt);
  k_attn<<<dim3(128, 8), dim3(512), 0, stream>>>(qkv, vt, sinks, tab, attnO);
  // out-proj: C[2048][2880] (N padded 3072), tile 128x96, grid (32,16) = 512 blocks
  k_gemm6<1, 96><<<dim3(32, 16), dim3(256), 0, stream>>>(attnO, woutT, (void*)out,
                                                         x, 3072, 2880, 4096);
}

// Round 15
// 172.063 us; speedup vs baseline: 1.7997x; 1.0286x over previous
//
#include <hip/hip_runtime.h>
#include <math.h>

typedef unsigned short u16;
typedef unsigned int u32;
typedef short bf4 __attribute__((ext_vector_type(4)));
typedef __bf16 bfv8 __attribute__((ext_vector_type(8)));
typedef float f4 __attribute__((ext_vector_type(4)));

#define SEQ 2048
#define HID 2880
#define KPAD 2944
#define QKVN 5120

static __device__ __forceinline__ u16 f2bf(float x) {
  union { float f; u32 u; } v; v.f = x;
  u32 r = v.u + 0x7fffu + ((v.u >> 16) & 1u);
  return (u16)(r >> 16);
}
static __device__ __forceinline__ float bf2f(u16 s) {
  union { u32 u; float f; } v; v.u = ((u32)s) << 16;
  return v.f;
}
static __device__ __forceinline__ void gl_lds16(const void* g, void* l) {
  __builtin_amdgcn_global_load_lds((const __attribute__((address_space(1))) u32*)g,
                                   (__attribute__((address_space(3))) u32*)l, 16, 0, 0);
}
#define MFMA(a, b, c) __builtin_amdgcn_mfma_f32_16x16x16bf16_1k(a, b, c, 0, 0, 0)
#define MFMA32(a, b, c) __builtin_amdgcn_mfma_f32_16x16x32_bf16(a, b, c, 0, 0, 0)
#define BAR __builtin_amdgcn_s_barrier()
#define SCHEDB __builtin_amdgcn_sched_barrier(0)
#define VMCNT0 asm volatile("s_waitcnt vmcnt(0)" ::: "memory")
#define LGKM0 asm volatile("s_waitcnt lgkmcnt(0)" ::: "memory")
#define LGKM2 asm volatile("s_waitcnt lgkmcnt(2)" ::: "memory")

// ---- merged prep: [0,2048) rmsnorm+rope-table | [2048,5728) convT qkv_w
// ----              [5728,8800) convT out_w.  All memory-bound, co-scheduled.
__global__ __launch_bounds__(256) void k_prep(const float* __restrict__ x,
                                              const float* __restrict__ norm_w,
                                              const float* __restrict__ qkv_w,
                                              const float* __restrict__ out_w,
                                              u16* __restrict__ t,
                                              float* __restrict__ tab,
                                              u16* __restrict__ wqkvT,
                                              u16* __restrict__ woutT) {
  __shared__ __align__(16) u16 shb[64 * 65 + 16];  // union: convT tile / rms red
  const int bid = blockIdx.x;
  if (bid < 2048) {
    // ---------------- RMSNorm row + rope table ----------------
    const int row = bid;
    if (threadIdx.x < 32) {
      const int d = threadIdx.x;
      const float low = 8.0927791f, high = 17.3980236f, conc = 1.3465735903f;
      float freq = powf(150000.0f, (float)d * (1.0f / 32.0f));
      float r01 = fminf(fmaxf(((float)d - low) / (high - low), 0.f), 1.f);
      float invf = (1.0f / (32.0f * freq)) * r01 + (1.0f / freq) * (1.f - r01);
      float ang = (float)row * invf;
      tab[(size_t)row * 64 + d] = cosf(ang) * conc;
      tab[(size_t)row * 64 + 32 + d] = sinf(ang) * conc;
    }
    const float* xr = x + (size_t)row * HID;
    float ss = 0.f;
    for (int i = threadIdx.x; i < 720; i += 256) {
      float4 v = ((const float4*)xr)[i];
      ss += v.x * v.x + v.y * v.y + v.z * v.z + v.w * v.w;
    }
#pragma unroll
    for (int m = 1; m < 64; m <<= 1) ss += __shfl_xor(ss, m);
    float* red = (float*)(shb + 64 * 65);
    if ((threadIdx.x & 63) == 0) red[threadIdx.x >> 6] = ss;
    __syncthreads();
    float sc = rsqrtf((red[0] + red[1] + red[2] + red[3]) * (1.0f / HID) + 1e-5f);
    u16* tr = t + (size_t)row * KPAD;
    for (int i = threadIdx.x; i < 720; i += 256) {
      float4 v = ((const float4*)xr)[i];
      float4 wv = ((const float4*)norm_w)[i];
      ushort4 o;
      o.x = f2bf(v.x * sc * wv.x);
      o.y = f2bf(v.y * sc * wv.y);
      o.z = f2bf(v.z * sc * wv.z);
      o.w = f2bf(v.w * sc * wv.w);
      ((ushort4*)tr)[i] = o;
    }
    if (threadIdx.x < 16) ((ushort4*)tr)[720 + threadIdx.x] = make_ushort4(0, 0, 0, 0);
  } else {
    // ---------------- transpose+convert weight tile ----------------
    const float* W;
    u16* WT;
    int K, Kpad, Nsrc, n0, k0;
    if (bid < 2048 + 3680) {
      int b = bid - 2048;                 // 80 x 46 tiles
      W = qkv_w; WT = wqkvT; K = 2880; Kpad = KPAD; Nsrc = 5120;
      n0 = (b % 80) * 64; k0 = (b / 80) * 64;
    } else {
      int b = bid - 5728;                 // 48 x 64 tiles
      W = out_w; WT = woutT; K = 4096; Kpad = 4096; Nsrc = 2880;
      n0 = (b % 48) * 64; k0 = (b / 48) * 64;
    }
    u16 (*tile)[65] = (u16(*)[65])shb;    // [n_local][k_local]
    for (int s = threadIdx.x; s < 1024; s += 256) {
      int r = s >> 4, c4 = (s & 15) * 4;
      int kk = k0 + r, nn = n0 + c4;
      float4 v = make_float4(0.f, 0.f, 0.f, 0.f);
      if (kk < K && nn < Nsrc) v = *(const float4*)&W[(size_t)kk * Nsrc + nn];
      tile[c4 + 0][r] = f2bf(v.x);
      tile[c4 + 1][r] = f2bf(v.y);
      tile[c4 + 2][r] = f2bf(v.z);
      tile[c4 + 3][r] = f2bf(v.w);
    }
    __syncthreads();
    for (int s = threadIdx.x; s < 512; s += 256) {
      int r = s >> 3, c8 = (s & 7) * 8;
      u32 p0 = tile[r][c8 + 0] | ((u32)tile[r][c8 + 1] << 16);
      u32 p1 = tile[r][c8 + 2] | ((u32)tile[r][c8 + 3] << 16);
      u32 p2 = tile[r][c8 + 4] | ((u32)tile[r][c8 + 5] << 16);
      u32 p3 = tile[r][c8 + 6] | ((u32)tile[r][c8 + 7] << 16);
      *(uint4*)&WT[(size_t)(n0 + r) * Kpad + k0 + c8] = make_uint4(p0, p1, p2, p3);
    }
  }
}

// -- GEMM 128xBN, BK=64, 4 waves (2Mx2N), 2 blocks/CU, 1-barrier counted-lgkm loop --
// (R9 best-measured structure, verbatim.)  C[M][N] = A[M][K] * BT[N][K]^T.
template <int MODE, int BN>  // MODE 0: bf16 ; 1: f32 + residual, guard col<Nout
__global__ __launch_bounds__(256, 2) void k_gemm6(const u16* __restrict__ A,
                                                  const u16* __restrict__ BT,
                                                  void* __restrict__ Cv,
                                                  const float* __restrict__ resid,
                                                  int N, int Nout, int K) {
  constexpr int WN = BN / 2;      // wave n-extent (80 or 48)
  constexpr int NF = WN / 16;     // B chunks per wave (5 or 3)
  constexpr int ABY = 128 * 128;  // A K-tile bytes (16 KB)
  constexpr int BBY = BN * 128;   // B K-tile bytes (20 / 12 KB)
  constexpr int TILE = ABY + BBY;
  constexpr int NBC = BBY / 4096; // B stage calls (256 thr x 16B)
  __shared__ __align__(16) char lds[2 * TILE];
  const int n0 = blockIdx.x * BN, m0 = blockIdx.y * 128;
  const int tid = threadIdx.x;    // 0..255, 4 waves
  const int l = tid & 63, w = tid >> 6;
  const int wm = w >> 1, wn = w & 1;  // 2M x 2N waves
  const int g = l >> 4, q = l & 15;
  const int NT = K >> 6;

#define STAGE_A(bo_, kt, p) { const int slot = (p)*256 + tid; \
    const int row = slot >> 3, c = slot & 7; \
    gl_lds16(A + (size_t)(m0 + row) * K + (kt)*64 + ((c ^ (row & 7)) * 8), \
             lds + (bo_) + slot * 16); }
#define STAGE_B(bo_, kt, p) { const int slot = (p)*256 + tid; \
    const int row = slot >> 3, c = slot & 7; \
    gl_lds16(BT + (size_t)(n0 + row) * K + (kt)*64 + ((c ^ (row & 7)) * 8), \
             lds + (bo_) + ABY + slot * 16); }
#define LDB2(DST, nf_) { const int r_ = wn * WN + (nf_)*16 + q; \
    DST[0] = *(const bfv8*)(lds + bo + ABY + r_ * 128 + (((g) ^ (r_ & 7)) << 4)); \
    DST[1] = *(const bfv8*)(lds + bo + ABY + r_ * 128 + (((4 + g) ^ (r_ & 7)) << 4)); }

  f4 acc[4][NF] = {};
  // prologue: stage tile 0, drain, barrier
#pragma unroll
  for (int p = 0; p < 4; ++p) STAGE_A(0, 0, p);
#pragma unroll
  for (int p = 0; p < NBC; ++p) STAGE_B(0, 0, p);
  VMCNT0; SCHEDB; BAR;

  for (int t = 0; t < NT; ++t) {
    const int bo = (t & 1) * TILE;  // current buffer
    const int so = bo ^ TILE;       // stage buffer (next tile)
    // issue next-tile stages first (latency covered by this tile's compute)
    if (t + 1 < NT) {
#pragma unroll
      for (int p = 0; p < 4; ++p) STAGE_A(so, t + 1, p);
#pragma unroll
      for (int p = 0; p < NBC; ++p) STAGE_B(so, t + 1, p);
    }
    SCHEDB;
    bfv8 af[4][2], bb[2][2];
    // entry: A frags (8 reads) + B chunk 0 (2 reads) | B chunk 1 (2 reads)
#pragma unroll
    for (int mf = 0; mf < 4; ++mf) {
      const int r = wm * 64 + mf * 16 + q;
      af[mf][0] = *(const bfv8*)(lds + bo + r * 128 + (((g) ^ (r & 7)) << 4));
      af[mf][1] = *(const bfv8*)(lds + bo + r * 128 + (((4 + g) ^ (r & 7)) << 4));
    }
    LDB2(bb[0], 0);
    SCHEDB;                 // pin boundary: [A,b0] | b1
    LDB2(bb[1], 1);
    __builtin_amdgcn_s_setprio(1);
#pragma unroll
    for (int nf = 0; nf < NF; ++nf) {
      if (nf == NF - 1) { LGKM0; } else { LGKM2; }  // chunk nf landed; nf+1 in flight
      SCHEDB;
#pragma unroll
      for (int mf = 0; mf < 4; ++mf) {
        acc[mf][nf] = MFMA32(af[mf][0], bb[nf & 1][0], acc[mf][nf]);
        acc[mf][nf] = MFMA32(af[mf][1], bb[nf & 1][1], acc[mf][nf]);
      }
      if (nf + 2 < NF) LDB2(bb[nf & 1], nf + 2);  // refill freed slot
    }
    __builtin_amdgcn_s_setprio(0);
    VMCNT0;  // next-tile stages issued at tile start: aged ~1 full tile -> near-free
    SCHEDB; BAR;
  }
  // epilogue
#pragma unroll
  for (int mf = 0; mf < 4; ++mf)
#pragma unroll
    for (int nf = 0; nf < NF; ++nf)
#pragma unroll
      for (int r = 0; r < 4; ++r) {
        int row = m0 + wm * 64 + mf * 16 + g * 4 + r;
        int col = n0 + wn * WN + nf * 16 + q;
        if constexpr (MODE == 0) {
          ((u16*)Cv)[(size_t)row * N + col] = f2bf(acc[mf][nf][r]);
        } else {
          if (col < Nout)
            ((float*)Cv)[(size_t)row * Nout + col] =
                acc[mf][nf][r] + resid[(size_t)row * Nout + col];
        }
      }
#undef STAGE_A
#undef STAGE_B
#undef LDB2
}

// ---------------- V transpose: qkv v-cols -> vt[8][64][2048] bf16 ----------------
__global__ __launch_bounds__(256) void k_vtrans(const u16* __restrict__ qkv,
                                                u16* __restrict__ vt) {
  __shared__ u16 tile[64][72];  // [t_local][d]
  const int t0 = blockIdx.x * 64, h = blockIdx.y;
  for (int s = threadIdx.x; s < 512; s += 256) {
    int r = s >> 3, c8 = (s & 7) * 8;
    uint4 v = *(const uint4*)&qkv[(size_t)(t0 + r) * QKVN + 4608 + h * 64 + c8];
    *(uint4*)&tile[r][c8] = v;
  }
  __syncthreads();
  for (int s = threadIdx.x; s < 512; s += 256) {
    int d = s >> 3, c8 = (s & 7) * 8;
    u32 p0 = tile[c8 + 0][d] | ((u32)tile[c8 + 1][d] << 16);
    u32 p1 = tile[c8 + 2][d] | ((u32)tile[c8 + 3][d] << 16);
    u32 p2 = tile[c8 + 4][d] | ((u32)tile[c8 + 5][d] << 16);
    u32 p3 = tile[c8 + 6][d] | ((u32)tile[c8 + 7][d] << 16);
    *(uint4*)&vt[((size_t)h * 64 + d) * SEQ + t0 + c8] = make_uint4(p0, p1, p2, p3);
  }
}

// ------- Attention: sliding window 128 + sink, GQA 8x8, RoPE fused (table) -------
__global__ __launch_bounds__(512) void k_attn(const u16* __restrict__ qkv,
                                              const u16* __restrict__ vt,
                                              const float* __restrict__ sinks,
                                              const float* __restrict__ tab,
                                              u16* __restrict__ attn) {
  __shared__ u16 lK[144 * 72];       // [key][dim], stride 72
  __shared__ u16 lV[64 * 152];       // [dim][key], stride 152
  __shared__ u16 lP[8 * 16 * 148];   // per-wave [q][key], stride 148
  const int t0 = blockIdx.x * 16;
  const int h = blockIdx.y;
  const int j0 = t0 - 128;
  const int tid = threadIdx.x;
  // stage RAW K rows (zero for j<0)
  for (int s = tid; s < 1152; s += 512) {
    int row = s >> 3, c = s & 7;
    int j = j0 + row;
    uint4 v = make_uint4(0, 0, 0, 0);
    if (j >= 0) v = *(const uint4*)&qkv[(size_t)j * QKVN + 4096 + h * 64 + c * 8];
    *(uint4*)&lK[row * 72 + c * 8] = v;
  }
  for (int s = tid; s < 1152; s += 512) {
    int d = s / 18, c = s - d * 18;
    int jb = j0 + c * 8;
    uint4 v = make_uint4(0, 0, 0, 0);
    if (jb >= 0) v = *(const uint4*)&vt[((size_t)h * 64 + d) * SEQ + jb];
    *(uint4*)&lV[d * 152 + c * 8] = v;
  }
  __syncthreads();
  // fused RoPE on K rows in LDS: 144 rows x 32 pairs
  for (int p = tid; p < 4608; p += 512) {
    int row = p >> 5, d = p & 31;
    int j = j0 + row;
    if (j >= 0) {
      float c = tab[(size_t)j * 64 + d];
      float s = tab[(size_t)j * 64 + 32 + d];
      int base = row * 72;
      float x1 = bf2f(lK[base + d]), x2 = bf2f(lK[base + 32 + d]);
      lK[base + d] = f2bf(x1 * c - x2 * s);
      lK[base + 32 + d] = f2bf(x2 * c + x1 * s);
    }
  }
  __syncthreads();
  const int w = tid >> 6, l = tid & 63;
  const int g = l >> 4, q = l & 15;
  const int hq = h * 8 + w;
  const float sink = sinks[hq];
  // load RAW Q fragments, apply RoPE in registers (pairs: ks0<->ks2, ks1<->ks3)
  bf4 qf[4];
  const u16* qrow = qkv + (size_t)(t0 + q) * QKVN + hq * 64;
#pragma unroll
  for (int ks = 0; ks < 4; ++ks) qf[ks] = *(const bf4*)&qrow[ks * 16 + g * 4];
  {
    const float* tb = tab + (size_t)(t0 + q) * 64;
    float c0[4], s0[4], c1[4], s1[4];
    *(float4*)c0 = *(const float4*)&tb[g * 4];
    *(float4*)s0 = *(const float4*)&tb[32 + g * 4];
    *(float4*)c1 = *(const float4*)&tb[16 + g * 4];
    *(float4*)s1 = *(const float4*)&tb[48 + g * 4];
#pragma unroll
    for (int i = 0; i < 4; ++i) {
      float x0 = bf2f((u16)qf[0][i]), x2 = bf2f((u16)qf[2][i]);
      qf[0][i] = (short)f2bf(x0 * c0[i] - x2 * s0[i]);
      qf[2][i] = (short)f2bf(x2 * c0[i] + x0 * s0[i]);
      float x1 = bf2f((u16)qf[1][i]), x3 = bf2f((u16)qf[3][i]);
      qf[1][i] = (short)f2bf(x1 * c1[i] - x3 * s1[i]);
      qf[3][i] = (short)f2bf(x3 * c1[i] + x1 * s1[i]);
    }
  }
  f4 sacc[9];
#pragma unroll
  for (int nt = 0; nt < 9; ++nt) {
    f4 z = {0.f, 0.f, 0.f, 0.f};
    sacc[nt] = z;
#pragma unroll
    for (int ks = 0; ks < 4; ++ks) {
      bf4 kf = *(const bf4*)&lK[(nt * 16 + q) * 72 + ks * 16 + g * 4];
      sacc[nt] = MFMA(qf[ks], kf, sacc[nt]);
    }
  }
  const float NEG = -__builtin_inff();
  float rmax[4] = {NEG, NEG, NEG, NEG};
#pragma unroll
  for (int nt = 0; nt < 9; ++nt)
#pragma unroll
    for (int r = 0; r < 4; ++r) {
      float sv = sacc[nt][r] * 0.125f;
      int it = t0 + g * 4 + r;
      int j = j0 + nt * 16 + q;
      bool ban = (j > it) || (it - j >= 128) || (j < 0);
      sv = ban ? NEG : sv;
      sacc[nt][r] = sv;
      rmax[r] = fmaxf(rmax[r], sv);
    }
#pragma unroll
  for (int r = 0; r < 4; ++r)
#pragma unroll
    for (int m = 1; m < 16; m <<= 1) rmax[r] = fmaxf(rmax[r], __shfl_xor(rmax[r], m));
  float ssum[4];
  u16* pbase = lP + w * (16 * 148);
#pragma unroll
  for (int r = 0; r < 4; ++r) {
    float mf = fmaxf(rmax[r], sink);
    float ps = 0.f;
#pragma unroll
    for (int nt = 0; nt < 9; ++nt) {
      float p = __expf(sacc[nt][r] - mf);
      pbase[(g * 4 + r) * 148 + nt * 16 + q] = f2bf(p);
      ps += p;
    }
#pragma unroll
    for (int m = 1; m < 16; m <<= 1) ps += __shfl_xor(ps, m);
    ssum[r] = ps + __expf(sink - mf);
  }
  f4 oacc[4] = {};
#pragma unroll
  for (int kt = 0; kt < 9; ++kt) {
    bf4 pa = *(const bf4*)&pbase[q * 148 + kt * 16 + g * 4];
#pragma unroll
    for (int nt = 0; nt < 4; ++nt) {
      bf4 vf = *(const bf4*)&lV[(nt * 16 + q) * 152 + kt * 16 + g * 4];
      oacc[nt] = MFMA(pa, vf, oacc[nt]);
    }
  }
#pragma unroll
  for (int nt = 0; nt < 4; ++nt)
#pragma unroll
    for (int r = 0; r < 4; ++r) {
      int row = t0 + g * 4 + r;
      attn[(size_t)row * 4096 + hq * 64 + nt * 16 + q] = f2bf(oacc[nt][r] / ssum[r]);
    }
}

extern "C" void kernel_launch(void* const* d_in, const int* in_sizes, int n_in,
                              void* d_out, int out_size, void* d_ws, size_t ws_size,
                              hipStream_t stream) {
  const float* x = (const float*)d_in[0];
  const float* norm_w = (const float*)d_in[1];
  const float* qkv_w = (const float*)d_in[2];
  const float* out_w = (const float*)d_in[3];
  const float* sinks = (const float*)d_in[4];
  float* out = (float*)d_out;
  char* ws = (char*)d_ws;
  // ws layout (bytes), total 90,963,968:
  u16* t     = (u16*)(ws);               // [2048][2944] = 12,058,624
  u16* wqkvT = (u16*)(ws + 12058624);    // [5120][2944] = 30,146,560 -> 42,205,184
  u16* qkv   = (u16*)(ws + 42205184);    // [2048][5120] = 20,971,520 -> 63,176,704
  u16* vt    = (u16*)(ws + 63176704);    // [8][64][2048] = 2,097,152 -> 65,273,856
  u16* woutT = (u16*)(ws + 65273856);    // [3072][4096] = 25,165,824 -> 90,439,680
  float* tab = (float*)(ws + 90439680);  // [2048][64] f32 = 524,288 -> 90,963,968
  u16* attnO = (u16*)(ws);               // alias t+wqkvT head (dead after QKV GEMM)

  // merged prep: rmsnorm (2048) + convT qkv (3680) + convT out (3072) = 8800 blocks
  k_prep<<<dim3(8800), dim3(256), 0, stream>>>(x, norm_w, qkv_w, out_w,
                                               t, tab, wqkvT, woutT);
  // QKV: C[2048][5120], tile 128x160, grid (32,16) = 512 blocks (2/CU, 4 waves each)
  k_gemm6<0, 160><<<dim3(32, 16), dim3(256), 0, stream>>>(t, wqkvT, (void*)qkv,
                                                          nullptr, 5120, 5120, KPAD);
  k_vtrans<<<dim3(32, 8), dim3(256), 0, stream>>>(qkv, vt);
  k_attn<<<dim3(128, 8), dim3(512), 0, stream>>>(qkv, vt, sinks, tab, attnO);
  // out-proj: C[2048][2880] (N padded 3072), tile 128x96, grid (32,16) = 512 blocks
  k_gemm6<1, 96><<<dim3(32, 16), dim3(256), 0, stream>>>(attnO, woutT, (void*)out,
                                                         x, 3072, 2880, 4096);
}